// Round 4
// baseline (2207.954 us; speedup 1.0000x reference)
//
#include <hip/hip_runtime.h>
#include <hip/hip_cooperative_groups.h>
#include <math.h>

namespace cg = cooperative_groups;

#define NVERT 8192
#define NEDGE 65536
#define NSUB 8
#define NCG 20
#define GRID 256
#define BLOCK 1024
#define DT 0.01f
#define KS 10000.0f
#define NGRP 16   // barrier groups
#define GSIZE 16  // blocks per group (NGRP*GSIZE == GRID)
#define NROW 4    // atomic-accumulator contention split
// 256x1024: the empirically valid cooperative geometry (512x512 never launches).
//
// R17 = R16 + dot-reduction OUT of the barrier chain.
// Falsified so far: R11 LDS adjacency (neutral); R12 sync-domain split (+17%);
// R14 cached-gather + agent-acquire fence (+243%: L2-invalidate per segment);
// R15 unroll 8 (+2%: gather is per-CU-miss-concurrency bound, not per-wave).
// R16 (flattened release): real but small (-25us) -> the in-shadow Pd->Gd
// reduce (load Pd ~600cy + store/drain Gd ~600cy + flag ~600cy, x160 bars)
// was the remaining serial chain, not the root/fan-out hops.
// R17: publish block dot-partials via MONOTONIC f64 hardware atomics into
// A[4][96] (row = blockIdx&3, max 64 adds/word); all barriers become the
// plain flattened fast_bar. Consumers park 384 A-loads under the gather and
// compute dot_k = A_now - A_prev (prev in regs; running-sum differencing ->
// no zeroing, no parity). In-block tree unchanged (deterministic); only the
// cross-block sum order becomes atomic-nondeterministic (~1e-15 rel on f64
// dots -> ulp-level f32 alpha jitter, invisible vs tolerance).
// Race safety (parked loads vs other blocks' future adds): MALL queues are
// DRAINED at every release (all blocks vmcnt(0) before arrive), parked loads
// are first entries post-release; any block's next adds trail its full
// ~1536-line gather. Same discipline the validated Gd-park used.
// R10 base: one thread per (vertex,batch); batch-innermost split planes
// (float2 xy + float z, relaxed agent atomics = sc1, fence-free); pipelined
// CG (1 barrier/iter) with neighbor-sum recurrences (gather only Ap).

struct Params {
  const float* action;   // [B][NE]
  const float* pos0;     // [B][NV][3]
  const float* vel0;     // [B][NV][3]
  const float* rest_len; // [NE]
  const float* mass;     // [NV]
  const int* edge_i;     // [NE]
  const int* edge_j;     // [NE]
  float* out;            // [B][NSUB][NV][3]
  float2* posXY;         // [NV*32] exchanged (sc1)
  float*  posZ;          // [NV*32]
  float2 *QXY0, *QXY1;   // ping-pong Ap / r0 staging (sc1)
  float  *QZ0,  *QZ1;
  float* rest_eff;       // [NE][32]  read-only after setup (cached)
  int* adj_off;          // [2NE] neighbor xy-plane byte offset (u*256), cached
  int* adjE_off;         // [2NE] edge byte offset (e*128), cached
  int* row_ptr;          // [NV+1]
  int* cursor;           // [NV]
  double* A;             // [NROW][96] monotonic dot accumulators (hw f64 atomics)
  unsigned* bar;         // [(2*NGRP+1)*32] uints: grp arrive cnts | unused
};

union U64F2 { unsigned long long u; float2 f; };
union U32F  { unsigned u; float f; };
union U64D  { unsigned long long u; double d; };

__device__ __forceinline__ float2 ld2_dev(const float2* p) {
  U64F2 r;
  r.u = __hip_atomic_load((const unsigned long long*)p, __ATOMIC_RELAXED, __HIP_MEMORY_SCOPE_AGENT);
  return r.f;
}
__device__ __forceinline__ void st2_dev(float2* p, float2 v) {
  U64F2 r; r.f = v;
  __hip_atomic_store((unsigned long long*)p, r.u, __ATOMIC_RELAXED, __HIP_MEMORY_SCOPE_AGENT);
}
__device__ __forceinline__ float ldf_dev(const float* p) {
  U32F r;
  r.u = __hip_atomic_load((const unsigned*)p, __ATOMIC_RELAXED, __HIP_MEMORY_SCOPE_AGENT);
  return r.f;
}
__device__ __forceinline__ void stf_dev(float* p, float v) {
  U32F r; r.f = v;
  __hip_atomic_store((unsigned*)p, r.u, __ATOMIC_RELAXED, __HIP_MEMORY_SCOPE_AGENT);
}
__device__ __forceinline__ double lddbl_dev(const double* p) {
  U64D r;
  r.u = __hip_atomic_load((const unsigned long long*)p, __ATOMIC_RELAXED, __HIP_MEMORY_SCOPE_AGENT);
  return r.d;
}

// Hardware f64 global atomic add (global_atomic_add_f64 on gfx90a+/gfx950).
// d_ws is hipMalloc'd coarse-grained memory, so unsafeAtomicAdd is exact.
__device__ __forceinline__ void atomic_add_f64_dev(double* p, double v) {
  unsafeAtomicAdd(p, v);
}

// Flattened hierarchical barrier. Arrive: one RMW on this block's group
// counter. Release: pollers watch ALL 16 group counters (one parallel RT).
// Preceding __syncthreads drains every wave's sc1 stores AND atomics
// (s_waitcnt vmcnt(0) before s_barrier), so arrival implies visibility.
__device__ __forceinline__ void fast_bar(unsigned* bar, unsigned ep) {
  __syncthreads();
  if (threadIdx.x == 0) {
    const unsigned g = blockIdx.x >> 4;
    __hip_atomic_fetch_add(bar + g * 32, 1u,
                           __ATOMIC_RELAXED, __HIP_MEMORY_SCOPE_AGENT);
    const unsigned tgt = GSIZE * ep;
    for (;;) {
      bool ok = true;
#pragma unroll
      for (int i = 0; i < NGRP; ++i)
        ok &= (__hip_atomic_load(bar + i * 32,
                                 __ATOMIC_RELAXED, __HIP_MEMORY_SCOPE_AGENT) >= tgt);
      if (ok) break;
      __builtin_amdgcn_s_sleep(1);
    }
  }
  __syncthreads();
}

// Publish block partial of 3 per-batch doubles into A[row][0..95] via
// monotonic hw f64 atomics. In-block tree (shuffle + LDS) is deterministic.
// No trailing __syncthreads — MUST be followed by fast_bar.
__device__ __forceinline__ void publish_atomic(double* Arow, double d0, double d1,
                                               double d2, double* lds) {
  d0 += __shfl_down(d0, 32);  // lane L += L+32: same batch, paired vertex
  d1 += __shfl_down(d1, 32);
  d2 += __shfl_down(d2, 32);
  const int lane = threadIdx.x & 63, w = threadIdx.x >> 6;
  if (lane < 32) {
    lds[w * 96 + lane] = d0;
    lds[w * 96 + 32 + lane] = d1;
    lds[w * 96 + 64 + lane] = d2;
  }
  __syncthreads();
  if (threadIdx.x < 96) {
    double s = 0.0;
#pragma unroll
    for (int ww = 0; ww < BLOCK / 64; ++ww) s += lds[ww * 96 + threadIdx.x];
    atomic_add_f64_dev(Arow + threadIdx.x, s);
  }
}

__global__ void __launch_bounds__(BLOCK) mass_spring_kernel(Params P) {
  cg::grid_group grid = cg::this_grid();
  __shared__ double lds_red[(BLOCK / 64) * 96];  // 12 KB
  __shared__ double lds_acc[96];                 // 768 B
  __shared__ int lds_scan[BLOCK];                // 4 KB

  const int tid = threadIdx.x;
  const int gtid = blockIdx.x * BLOCK + tid;
  const int b = tid & 31;
  const int v = gtid >> 5;
  const int vb = v * 32 + b;
  const int b8 = b * 8, b4 = b * 4;
  unsigned ep = 0;
  double prevq = 0.0;            // running A[.][q] snapshot (tid<96 only)
  double* const Arow = P.A + (size_t)(blockIdx.x & (NROW - 1)) * 96;

  // ---------- setup (real grid.syncs publish plain writes) ----------
  for (int i = gtid; i < NEDGE * 32; i += GRID * BLOCK) {
    const int e = i >> 5, bb = i & 31;
    P.rest_eff[e * 32 + bb] = P.rest_len[e] * (1.0f + P.action[bb * NEDGE + e]);
  }
  float3 pv, vv;
  pv.x = P.pos0[(b * NVERT + v) * 3 + 0];
  pv.y = P.pos0[(b * NVERT + v) * 3 + 1];
  pv.z = P.pos0[(b * NVERT + v) * 3 + 2];
  vv.x = P.vel0[(b * NVERT + v) * 3 + 0];
  vv.y = P.vel0[(b * NVERT + v) * 3 + 1];
  vv.z = P.vel0[(b * NVERT + v) * 3 + 2];
  st2_dev(&P.posXY[vb], make_float2(pv.x, pv.y));
  stf_dev(&P.posZ[vb], pv.z);
  if (gtid < NVERT) P.cursor[gtid] = 0;
  if (gtid < (2 * NGRP + 1) * 32) P.bar[gtid] = 0u;
  if (gtid < NROW * 96) P.A[gtid] = 0.0;
  grid.sync();

  if (gtid < NEDGE) {
    atomicAdd(&P.cursor[P.edge_i[gtid]], 1);
    atomicAdd(&P.cursor[P.edge_j[gtid]], 1);
  }
  grid.sync();

  if (blockIdx.x == 0) {  // exclusive scan of degrees, 8 per thread
    const int base = tid * (NVERT / BLOCK);
    int loc[NVERT / BLOCK];
    int sum = 0;
#pragma unroll
    for (int i = 0; i < NVERT / BLOCK; ++i) { loc[i] = P.cursor[base + i]; sum += loc[i]; }
    lds_scan[tid] = sum;
    __syncthreads();
    for (int off = 1; off < BLOCK; off <<= 1) {
      int t = 0;
      if (tid >= off) t = lds_scan[tid - off];
      __syncthreads();
      if (tid >= off) lds_scan[tid] += t;
      __syncthreads();
    }
    int run = lds_scan[tid] - sum;
#pragma unroll
    for (int i = 0; i < NVERT / BLOCK; ++i) {
      P.row_ptr[base + i] = run;
      P.cursor[base + i] = run;
      run += loc[i];
    }
    if (tid == BLOCK - 1) P.row_ptr[NVERT] = run;
  }
  grid.sync();

  if (gtid < NEDGE) {  // adjacency: xy-plane byte offsets (u*256)
    const int ei = P.edge_i[gtid], ej = P.edge_j[gtid];
    const int ai = atomicAdd(&P.cursor[ei], 1);
    P.adj_off[ai] = ej * 256; P.adjE_off[ai] = gtid * 128;
    const int aj = atomicAdd(&P.cursor[ej], 1);
    P.adj_off[aj] = ei * 256; P.adjE_off[aj] = gtid * 128;
  }
  grid.sync();  // adjacency/rest_eff/row_ptr now published everywhere

  const float m_v = P.mass[v];
  const int rbeg = P.row_ptr[v], rend = P.row_ptr[v + 1];
  const float degf = (float)(rend - rbeg);

  float2* qXYrd = P.QXY0; float2* qXYwr = P.QXY1;
  float*  qZrd  = P.QZ0;  float*  qZwr  = P.QZ1;

  for (int s = 0; s < NSUB; ++s) {
    // ---------- F: spring force; stage r0 into q planes ----------
    float fx = 0.f, fy = 0.f, fz = 0.f;
#pragma unroll 4
    for (int a = rbeg; a < rend; ++a) {
      const int off = P.adj_off[a];  // u*256
      const float2 pxy = ld2_dev((const float2*)((const char*)P.posXY + off + b8));
      const float  puz = ldf_dev((const float*)((const char*)P.posZ + (off >> 1) + b4));
      const float re = *(const float*)((const char*)P.rest_eff + P.adjE_off[a] + b4);
      const float dx = pv.x - pxy.x, dy = pv.y - pxy.y, dz = pv.z - puz;
      const float l = sqrtf(dx * dx + dy * dy + dz * dz);
      const float coef = -KS * (l - re) / fmaxf(l, 1e-6f);
      fx += coef * dx; fy += coef * dy; fz += coef * dz;
    }
    float3 rv;
    rv.x = m_v * vv.x + DT * fx;
    rv.y = m_v * vv.y + DT * (fy - 9.8f * m_v);
    rv.z = m_v * vv.z + DT * fz;
    st2_dev(&qXYrd[vb], make_float2(rv.x, rv.y));
    stf_dev(&qZrd[vb], rv.z);
    float3 xacc = make_float3(0.f, 0.f, 0.f);
    float3 pc = rv;                 // p_k (registers)
    float3 ap;                      // Ap_k (registers)
    float3 Sr, Sp;                  // neighbor sums of r_k, p_k (registers)
    fast_bar(P.bar, ++ep);

    // ---------- CG: one barrier per iteration, split-plane sc1 gather -------
    for (int k = 0; k < NCG; ++k) {
      if (k == 0) {
        float sx = 0.f, sy = 0.f, sz = 0.f;  // sum r0[u]
#pragma unroll 4
        for (int a = rbeg; a < rend; ++a) {
          const int off = P.adj_off[a];
          const float2 qxy = ld2_dev((const float2*)((const char*)qXYrd + off + b8));
          const float  qz  = ldf_dev((const float*)((const char*)qZrd + (off >> 1) + b4));
          sx += qxy.x; sy += qxy.y; sz += qz;
        }
        Sr = make_float3(sx, sy, sz);
        Sp = Sr;  // p0 = r0
        ap.x = (m_v + degf) * pc.x - Sp.x;
        ap.y = (m_v + degf) * pc.y - Sp.y;
        ap.z = (m_v + degf) * pc.z - Sp.z;
      } else {
        // pipeline: park the 4-row A loads first (queues are drained at every
        // release, so these are the first entries and land long before any
        // block's NEXT adds, which trail its full gather)
        double av0, av1, av2, av3;
        if (tid < 96) {
          av0 = lddbl_dev(P.A + tid);
          av1 = lddbl_dev(P.A + 96 + tid);
          av2 = lddbl_dev(P.A + 192 + tid);
          av3 = lddbl_dev(P.A + 288 + tid);
        }
        // gather S_q = sum Ap_{k-1}[u] (hides the A latency)
        float sx = 0.f, sy = 0.f, sz = 0.f;
#pragma unroll 4
        for (int a = rbeg; a < rend; ++a) {
          const int off = P.adj_off[a];
          const float2 qxy = ld2_dev((const float2*)((const char*)qXYrd + off + b8));
          const float  qz  = ldf_dev((const float*)((const char*)qZrd + (off >> 1) + b4));
          sx += qxy.x; sy += qxy.y; sz += qz;
        }
        // dots via running-sum differencing (no LDS tree, no zeroing)
        if (tid < 96) {
          const double anow = (av0 + av1) + (av2 + av3);
          lds_acc[tid] = anow - prevq;
          prevq = anow;
        }
        __syncthreads();
        const double rsx = lds_acc[b];        // |r_{k-1}|^2 (exact)
        const double pq  = lds_acc[32 + b];   // p.Ap
        const double qq  = lds_acc[64 + b];   // Ap.Ap
        const float alpha = (float)(rsx / (pq + 1e-12));
        const double rs_rec = (double)alpha * (double)alpha * qq - rsx;
        const float beta = (float)(rs_rec / (rsx + 1e-12));
        xacc.x += alpha * pc.x; xacc.y += alpha * pc.y; xacc.z += alpha * pc.z;
        rv.x -= alpha * ap.x; rv.y -= alpha * ap.y; rv.z -= alpha * ap.z;
        Sr.x -= alpha * sx; Sr.y -= alpha * sy; Sr.z -= alpha * sz;
        pc.x = rv.x + beta * pc.x; pc.y = rv.y + beta * pc.y; pc.z = rv.z + beta * pc.z;
        Sp.x = Sr.x + beta * Sp.x; Sp.y = Sr.y + beta * Sp.y; Sp.z = Sr.z + beta * Sp.z;
        ap.x = (m_v + degf) * pc.x - Sp.x;
        ap.y = (m_v + degf) * pc.y - Sp.y;
        ap.z = (m_v + degf) * pc.z - Sp.z;
      }
      if (k != NCG - 1) {  // k==NCG-1 Ap plane is never gathered: dead store
        st2_dev(&qXYwr[vb], make_float2(ap.x, ap.y));
        stf_dev(&qZwr[vb], ap.z);
      }
      publish_atomic(Arow,
                     (double)(rv.x * rv.x) + (double)(rv.y * rv.y) + (double)(rv.z * rv.z),
                     (double)(pc.x * ap.x) + (double)(pc.y * ap.y) + (double)(pc.z * ap.z),
                     (double)(ap.x * ap.x) + (double)(ap.y * ap.y) + (double)(ap.z * ap.z),
                     lds_red);
      fast_bar(P.bar, ++ep);
      float2* t2 = qXYrd; qXYrd = qXYwr; qXYwr = t2;
      float*  t1 = qZrd;  qZrd  = qZwr;  qZwr  = t1;
    }

    // ---------- W: final alpha, integrate, write out ----------
    {
      if (tid < 96) {
        const double anow = (lddbl_dev(P.A + tid) + lddbl_dev(P.A + 96 + tid))
                          + (lddbl_dev(P.A + 192 + tid) + lddbl_dev(P.A + 288 + tid));
        lds_acc[tid] = anow - prevq;
        prevq = anow;
      }
      __syncthreads();
      const double rsx = lds_acc[b];
      const double pq  = lds_acc[32 + b];
      const float alpha = (float)(rsx / (pq + 1e-12));
      xacc.x += alpha * pc.x; xacc.y += alpha * pc.y; xacc.z += alpha * pc.z;
      vv = xacc;
      pv.x += DT * vv.x; pv.y += DT * vv.y; pv.z += DT * vv.z;
      st2_dev(&P.posXY[vb], make_float2(pv.x, pv.y));
      stf_dev(&P.posZ[vb], pv.z);
      float* o = P.out + ((size_t)(b * NSUB + s) * NVERT + (size_t)v) * 3;
      o[0] = pv.x; o[1] = pv.y; o[2] = pv.z;  // plain: flushed at kernel end
      fast_bar(P.bar, ++ep);
    }
  }
}

extern "C" void kernel_launch(void* const* d_in, const int* in_sizes, int n_in,
                              void* d_out, int out_size, void* d_ws, size_t ws_size,
                              hipStream_t stream) {
  Params P;
  P.action = (const float*)d_in[0];
  P.pos0 = (const float*)d_in[1];
  P.vel0 = (const float*)d_in[2];
  P.rest_len = (const float*)d_in[3];
  P.mass = (const float*)d_in[4];
  P.edge_i = (const int*)d_in[5];
  P.edge_j = (const int*)d_in[6];
  P.out = (float*)d_out;

  char* w = (char*)d_ws;
  auto alloc = [&](size_t bytes) {
    char* p = w;
    w += (bytes + 255) & ~(size_t)255;
    return p;
  };
  const size_t xy_bytes = (size_t)NVERT * 32 * sizeof(float2);  // 2 MB
  const size_t z_bytes  = (size_t)NVERT * 32 * sizeof(float);   // 1 MB
  P.posXY = (float2*)alloc(xy_bytes);
  P.posZ  = (float*)alloc(z_bytes);
  P.QXY0  = (float2*)alloc(xy_bytes);
  P.QXY1  = (float2*)alloc(xy_bytes);
  P.QZ0   = (float*)alloc(z_bytes);
  P.QZ1   = (float*)alloc(z_bytes);
  P.rest_eff = (float*)alloc((size_t)NEDGE * 32 * sizeof(float));
  P.adj_off  = (int*)alloc((size_t)2 * NEDGE * sizeof(int));
  P.adjE_off = (int*)alloc((size_t)2 * NEDGE * sizeof(int));
  P.row_ptr  = (int*)alloc((size_t)(NVERT + 1) * sizeof(int));
  P.cursor   = (int*)alloc((size_t)NVERT * sizeof(int));
  P.A        = (double*)alloc((size_t)NROW * 96 * sizeof(double));
  P.bar      = (unsigned*)alloc((size_t)(2 * NGRP + 1) * 32 * sizeof(unsigned));

  void* args[] = { &P };
  hipLaunchCooperativeKernel(reinterpret_cast<void*>(mass_spring_kernel),
                             dim3(GRID), dim3(BLOCK), args, 0, stream);
}